// Round 1
// baseline (150.823 us; speedup 1.0000x reference)
//
#include <hip/hip_runtime.h>

static constexpr int CCOLS = 50257;
static constexpr int BROWS = 4096;
static constexpr int TPB   = 256;

// One block per row: online-softmax logsumexp + windowed gather dot.
__global__ __launch_bounds__(TPB) void row_loss_kernel(
    const float* __restrict__ preds,
    const int*   __restrict__ labels,
    const float* __restrict__ window,
    int L,
    float* __restrict__ row_loss)
{
    const int row = blockIdx.x;
    const size_t base = (size_t)row * CCOLS;
    const float* __restrict__ p = preds + base;
    const int tid = threadIdx.x;

    float m = -1.0e30f;   // finite sentinel: avoids NaN from exp(-inf - -inf)
    float s = 0.0f;

    // Row base alignment: base % 4 == row % 4 (50257 ≡ 1 mod 4). Align for float4.
    const int head = (int)((4 - (base & 3)) & 3);
    const int nvec = (CCOLS - head) >> 2;
    const int tail_start = head + nvec * 4;

    const float4* __restrict__ p4 = (const float4*)(p + head);
    for (int i = tid; i < nvec; i += TPB) {
        float4 v = p4[i];
        float xm = fmaxf(fmaxf(v.x, v.y), fmaxf(v.z, v.w));
        if (xm > m) { s *= __expf(m - xm); m = xm; }  // rare rescale (~1 exp/elem total)
        s += __expf(v.x - m) + __expf(v.y - m) + __expf(v.z - m) + __expf(v.w - m);
    }
    if (tid == 0) {
        for (int i = 0; i < head; ++i) {
            float x = p[i];
            if (x > m) { s *= __expf(m - x); m = x; }
            s += __expf(x - m);
        }
        for (int i = tail_start; i < CCOLS; ++i) {
            float x = p[i];
            if (x > m) { s *= __expf(m - x); m = x; }
            s += __expf(x - m);
        }
    }

    // Wave-64 butterfly-free shfl_down reduce of (m, s) online pairs.
    for (int off = 32; off > 0; off >>= 1) {
        float mo = __shfl_down(m, off);
        float so = __shfl_down(s, off);
        float mn = fmaxf(m, mo);
        s = s * __expf(m - mn) + so * __expf(mo - mn);
        m = mn;
    }

    __shared__ float sm[TPB / 64], ss[TPB / 64];
    const int wave = tid >> 6, lane = tid & 63;
    if (lane == 0) { sm[wave] = m; ss[wave] = s; }
    __syncthreads();

    if (tid == 0) {
        m = sm[0]; s = ss[0];
        #pragma unroll
        for (int w = 1; w < TPB / 64; ++w) {
            float mo = sm[w], so = ss[w];
            float mn = fmaxf(m, mo);
            s = s * __expf(m - mn) + so * __expf(mo - mn);
            m = mn;
        }
        // Windowed dot around the label; window truncated (not renormalized) at edges.
        const int lab  = labels[row];
        const int half = L >> 1;
        float dot = 0.0f, wsum = 0.0f;
        for (int k = 0; k < L; ++k) {
            int pos = lab + k - half;
            if (pos >= 0 && pos < CCOLS) {
                float w = window[k];
                dot = fmaf(w, p[pos], dot);
                wsum += w;
            }
        }
        row_loss[row] = wsum * (m + __logf(s)) - dot;
    }
}

// Deterministic fixed-order reduction: per-thread strided sum + LDS tree.
__global__ __launch_bounds__(256) void reduce_kernel(
    const float* __restrict__ row_loss, float* __restrict__ out, int n)
{
    __shared__ float buf[256];
    float acc = 0.0f;
    for (int i = threadIdx.x; i < n; i += 256) acc += row_loss[i];
    buf[threadIdx.x] = acc;
    __syncthreads();
    for (int off = 128; off > 0; off >>= 1) {
        if ((int)threadIdx.x < off) buf[threadIdx.x] += buf[threadIdx.x + off];
        __syncthreads();
    }
    if (threadIdx.x == 0) out[0] = buf[0] / (float)n;
}

extern "C" void kernel_launch(void* const* d_in, const int* in_sizes, int n_in,
                              void* d_out, int out_size, void* d_ws, size_t ws_size,
                              hipStream_t stream)
{
    const float* preds  = (const float*)d_in[0];
    const int*   labels = (const int*)d_in[1];
    const float* window = (const float*)d_in[2];
    const int L = in_sizes[2];

    float* out = (float*)d_out;
    float* rl  = (float*)d_ws;   // 4096 floats of per-row loss (written every call)

    row_loss_kernel<<<BROWS, TPB, 0, stream>>>(preds, labels, window, L, rl);
    reduce_kernel<<<1, 256, 0, stream>>>(rl, out, BROWS);
}

// Round 2
// 138.445 us; speedup vs baseline: 1.0894x; 1.0894x over previous
//
#include <hip/hip_runtime.h>

static constexpr int CCOLS = 50257;
static constexpr int BROWS = 4096;
static constexpr int TPB   = 256;

typedef float f32x4 __attribute__((ext_vector_type(4)));

// One block per row: online-softmax logsumexp + windowed gather dot.
// Unroll-by-2 with two independent (m,s) chains -> 2 loads in flight/thread.
__global__ __launch_bounds__(TPB) void row_loss_kernel(
    const float* __restrict__ preds,
    const int*   __restrict__ labels,
    const float* __restrict__ window,
    int L,
    float* __restrict__ row_loss)
{
    const int row = blockIdx.x;
    const size_t base = (size_t)row * CCOLS;
    const float* __restrict__ p = preds + base;
    const int tid = threadIdx.x;

    float m0 = -1.0e30f, s0 = 0.0f;   // finite sentinel: avoids exp(-inf - -inf)
    float m1 = -1.0e30f, s1 = 0.0f;

    // Row base alignment: base % 4 == row % 4 (50257 mod 4 == 1). Align for float4.
    const int head = (int)((4 - (base & 3)) & 3);
    const int nvec = (CCOLS - head) >> 2;
    const int tail_start = head + nvec * 4;

    const f32x4* __restrict__ p4 = (const f32x4*)(p + head);

    int i = tid;
    for (; i + TPB < nvec; i += 2 * TPB) {
        f32x4 a = __builtin_nontemporal_load(p4 + i);
        f32x4 b = __builtin_nontemporal_load(p4 + i + TPB);
        float am = fmaxf(fmaxf(a[0], a[1]), fmaxf(a[2], a[3]));
        float bm = fmaxf(fmaxf(b[0], b[1]), fmaxf(b[2], b[3]));
        if (am > m0) { s0 *= __expf(m0 - am); m0 = am; }
        if (bm > m1) { s1 *= __expf(m1 - bm); m1 = bm; }
        s0 += __expf(a[0] - m0) + __expf(a[1] - m0) + __expf(a[2] - m0) + __expf(a[3] - m0);
        s1 += __expf(b[0] - m1) + __expf(b[1] - m1) + __expf(b[2] - m1) + __expf(b[3] - m1);
    }
    for (; i < nvec; i += TPB) {
        f32x4 a = __builtin_nontemporal_load(p4 + i);
        float am = fmaxf(fmaxf(a[0], a[1]), fmaxf(a[2], a[3]));
        if (am > m0) { s0 *= __expf(m0 - am); m0 = am; }
        s0 += __expf(a[0] - m0) + __expf(a[1] - m0) + __expf(a[2] - m0) + __expf(a[3] - m0);
    }

    // Merge the two chains.
    float m = fmaxf(m0, m1);
    float s = s0 * __expf(m0 - m) + s1 * __expf(m1 - m);

    if (tid == 0) {
        for (int k = 0; k < head; ++k) {
            float x = p[k];
            if (x > m) { s *= __expf(m - x); m = x; }
            s += __expf(x - m);
        }
        for (int k = tail_start; k < CCOLS; ++k) {
            float x = p[k];
            if (x > m) { s *= __expf(m - x); m = x; }
            s += __expf(x - m);
        }
    }

    // Wave-64 shfl_down reduce of (m, s) online pairs.
    for (int off = 32; off > 0; off >>= 1) {
        float mo = __shfl_down(m, off);
        float so = __shfl_down(s, off);
        float mn = fmaxf(m, mo);
        s = s * __expf(m - mn) + so * __expf(mo - mn);
        m = mn;
    }

    __shared__ float sm[TPB / 64], ss[TPB / 64];
    const int wave = tid >> 6, lane = tid & 63;
    if (lane == 0) { sm[wave] = m; ss[wave] = s; }
    __syncthreads();

    if (tid == 0) {
        m = sm[0]; s = ss[0];
        #pragma unroll
        for (int w = 1; w < TPB / 64; ++w) {
            float mo = sm[w], so = ss[w];
            float mn = fmaxf(m, mo);
            s = s * __expf(m - mn) + so * __expf(mo - mn);
            m = mn;
        }
        // Windowed dot around the label; window truncated (not renormalized) at edges.
        const int lab  = labels[row];
        const int half = L >> 1;
        float dot = 0.0f, wsum = 0.0f;
        for (int k = 0; k < L; ++k) {
            int pos = lab + k - half;
            if (pos >= 0 && pos < CCOLS) {
                float w = window[k];
                dot = fmaf(w, p[pos], dot);
                wsum += w;
            }
        }
        row_loss[row] = wsum * (m + __logf(s)) - dot;
    }
}

// Deterministic fixed-order reduction: per-thread strided sum + LDS tree.
__global__ __launch_bounds__(256) void reduce_kernel(
    const float* __restrict__ row_loss, float* __restrict__ out, int n)
{
    __shared__ float buf[256];
    float acc = 0.0f;
    for (int i = threadIdx.x; i < n; i += 256) acc += row_loss[i];
    buf[threadIdx.x] = acc;
    __syncthreads();
    for (int off = 128; off > 0; off >>= 1) {
        if ((int)threadIdx.x < off) buf[threadIdx.x] += buf[threadIdx.x + off];
        __syncthreads();
    }
    if (threadIdx.x == 0) out[0] = buf[0] / (float)n;
}

extern "C" void kernel_launch(void* const* d_in, const int* in_sizes, int n_in,
                              void* d_out, int out_size, void* d_ws, size_t ws_size,
                              hipStream_t stream)
{
    const float* preds  = (const float*)d_in[0];
    const int*   labels = (const int*)d_in[1];
    const float* window = (const float*)d_in[2];
    const int L = in_sizes[2];

    float* out = (float*)d_out;
    float* rl  = (float*)d_ws;   // 4096 floats of per-row loss (written every call)

    row_loss_kernel<<<BROWS, TPB, 0, stream>>>(preds, labels, window, L, rl);
    reduce_kernel<<<1, 256, 0, stream>>>(rl, out, BROWS);
}